// Round 9
// baseline (1036.228 us; speedup 1.0000x reference)
//
#include <hip/hip_runtime.h>
#include <hip/hip_bf16.h>

// DeBERTa layer: B=16,S=512,H=1024,NH=8,HD=128,FF=3072.
// R17: dense GEMM moved to BK=64 (half the barriers per K, 32 MFMA per
// barrier-pair). 128B-pitch LDS rows with chunk-XOR ^(row&7) on write
// (via global col permutation) and read -> uniform 8-slot spread (the
// zero-conflict multiplicity measured in R15/R16). Fused attention and
// all other kernels unchanged from R16.
#define BB  16
#define SS  512
#define HH  1024
#define NHH 8
#define HDD 128
#define FFF 3072
#define TT  (BB * SS)   // 8192 tokens

typedef __hip_bfloat16 bf16;
typedef short s8v __attribute__((ext_vector_type(8)));   // 8 bf16 bits (4 VGPRs)
typedef float f4v __attribute__((ext_vector_type(4)));   // 4 f32 acc

__device__ __forceinline__ float bf2f(bf16 v) { return __bfloat162float(v); }
__device__ __forceinline__ bf16 f2bf(float f) { return __float2bfloat16(f); }
__device__ __forceinline__ float us2f(unsigned short u) {
  union { unsigned int i; float f; } c; c.i = (unsigned int)u << 16; return c.f;
}

// ---------------- Embedding LayerNorm (f32 in -> bf16 out) ----------------------
__global__ void embed_ln_kernel(const float* __restrict__ x, const float* __restrict__ pos,
                                const float* __restrict__ g, const float* __restrict__ bta,
                                bf16* __restrict__ h) {
  int t = blockIdx.x;
  int s = t & (SS - 1);
  int tid = threadIdx.x;
  const float* xr = x + (size_t)t * HH;
  const float* pr = pos + (size_t)s * HH;
  float vals[4];
  float sum = 0.f;
#pragma unroll
  for (int i = 0; i < 4; i++) {
    int c = tid + i * 256;
    vals[i] = xr[c] + pr[c];
    sum += vals[i];
  }
  __shared__ float red[4];
#pragma unroll
  for (int off = 32; off > 0; off >>= 1) sum += __shfl_down(sum, off, 64);
  if ((tid & 63) == 0) red[tid >> 6] = sum;
  __syncthreads();
  float mean = (red[0] + red[1] + red[2] + red[3]) * (1.f / HH);
  float vsum = 0.f;
#pragma unroll
  for (int i = 0; i < 4; i++) { float d = vals[i] - mean; vsum += d * d; }
  __syncthreads();
#pragma unroll
  for (int off = 32; off > 0; off >>= 1) vsum += __shfl_down(vsum, off, 64);
  if ((tid & 63) == 0) red[tid >> 6] = vsum;
  __syncthreads();
  float rstd = rsqrtf((red[0] + red[1] + red[2] + red[3]) * (1.f / HH) + 1e-7f);
  bf16* hr = h + (size_t)t * HH;
#pragma unroll
  for (int i = 0; i < 4; i++) {
    int c = tid + i * 256;
    hr[c] = f2bf((vals[i] - mean) * rstd * g[c] + bta[c]);
  }
}

// ------- a(bf16)+res(bf16) -> LN -> out (OUT_F32 ? float : bf16) ---------------
template <int OUT_F32>
__global__ void add_ln_kernel(const bf16* __restrict__ a, const bf16* __restrict__ res,
                              const float* __restrict__ g, const float* __restrict__ bta,
                              void* __restrict__ outv) {
  int t = blockIdx.x;
  int tid = threadIdx.x;
  const bf16* ar = a + (size_t)t * HH;
  const bf16* rr = res + (size_t)t * HH;
  float vals[4];
  float sum = 0.f;
#pragma unroll
  for (int i = 0; i < 4; i++) {
    int c = tid + i * 256;
    vals[i] = bf2f(ar[c]) + bf2f(rr[c]);
    sum += vals[i];
  }
  __shared__ float red[4];
#pragma unroll
  for (int off = 32; off > 0; off >>= 1) sum += __shfl_down(sum, off, 64);
  if ((tid & 63) == 0) red[tid >> 6] = sum;
  __syncthreads();
  float mean = (red[0] + red[1] + red[2] + red[3]) * (1.f / HH);
  float vsum = 0.f;
#pragma unroll
  for (int i = 0; i < 4; i++) { float d = vals[i] - mean; vsum += d * d; }
  __syncthreads();
#pragma unroll
  for (int off = 32; off > 0; off >>= 1) vsum += __shfl_down(vsum, off, 64);
  if ((tid & 63) == 0) red[tid >> 6] = vsum;
  __syncthreads();
  float rstd = rsqrtf((red[0] + red[1] + red[2] + red[3]) * (1.f / HH) + 1e-7f);
#pragma unroll
  for (int i = 0; i < 4; i++) {
    int c = tid + i * 256;
    float o = (vals[i] - mean) * rstd * g[c] + bta[c];
    if (OUT_F32)
      ((float*)outv)[(size_t)t * HH + c] = o;
    else
      ((bf16*)outv)[(size_t)t * HH + c] = f2bf(o);
  }
}

// ---- weight convert+transpose: W[K,N] f32 -> Wt[N,K] bf16 (K fixed per call) --
__global__ void convert_w_kernel(const float* __restrict__ W, bf16* __restrict__ Wt,
                                 int K, int N) {
  __shared__ float tile[32][33];
  int n0 = blockIdx.x * 32, k0 = blockIdx.y * 32;
#pragma unroll
  for (int it = 0; it < 4; it++) {
    int idx = threadIdx.x + it * 256;
    int ty = idx >> 5, tx = idx & 31;
    tile[ty][tx] = W[(size_t)(k0 + ty) * N + n0 + tx];
  }
  __syncthreads();
#pragma unroll
  for (int it = 0; it < 4; it++) {
    int idx = threadIdx.x + it * 256;
    int ty = idx >> 5, tx = idx & 31;
    Wt[(size_t)(n0 + ty) * K + k0 + tx] = f2bf(tile[tx][ty]);
  }
}

// ---- concat qkv bias: [qbias | 0 | vbias] (f32) -------------------------------
__global__ void build_qkv_bias_kernel(const float* __restrict__ qb,
                                      const float* __restrict__ vb,
                                      float* __restrict__ o) {
  int i = blockIdx.x * 256 + threadIdx.x;  // 0..3071
  float v = 0.f;
  if (i < HH) v = qb[i];
  else if (i >= 2 * HH) v = vb[i - 2 * HH];
  o[i] = v;
}

// ---- V transpose per head: qkv v-cols -> vt[b,h,dim,key] (bf16) ---------------
__global__ void transpose_v_kernel(const bf16* __restrict__ v, bf16* __restrict__ vt) {
  __shared__ unsigned short tile[32][33];
  int bh = blockIdx.z;
  int s0 = blockIdx.x * 32, d0 = blockIdx.y * 32;
  int b = bh >> 3, hd = bh & 7;
  const unsigned short* vp = (const unsigned short*)v + ((size_t)b * SS) * (3 * HH) + hd * HDD;
  unsigned short* vtp = (unsigned short*)vt + (size_t)bh * HDD * SS;
#pragma unroll
  for (int it = 0; it < 4; it++) {
    int idx = threadIdx.x + it * 256;
    int ty = idx >> 5, tx = idx & 31;
    tile[ty][tx] = vp[(size_t)(s0 + ty) * (3 * HH) + d0 + tx];
  }
  __syncthreads();
#pragma unroll
  for (int it = 0; it < 4; it++) {
    int idx = threadIdx.x + it * 256;
    int ty = idx >> 5, tx = idx & 31;
    vtp[(size_t)(d0 + ty) * SS + s0 + tx] = tile[tx][ty];
  }
}

// ---- 128x128 MFMA GEMM, BK=64: reg-staging + prefetch + (row&7) chunk-XOR -----
// C = act((A @ Bt^T + bias)*scale). 4 waves x 4x4 16x16x32 MFMA, 2 k-subtiles
// per LDS tile -> 32 MFMA per barrier-pair. LDS [128][64] ushorts per operand
// (128B rows = bank-aligned). Chunk c of row r stored at c ^ (r&7): write side
// permutes the GLOBAL source column (thread t reads global chunk t&7, writes
// LDS chunk (t&7)^(r&7)); read XORs with l15&7. Wave spreads every b128
// access uniformly over all 8 16B slots (zero-conflict multiplicity).
template <int GELU>
__global__ __launch_bounds__(256)
void mfma_gemm_kernel(const bf16* __restrict__ A, int lda, long long sAb, long long sAh,
                      const bf16* __restrict__ Bt, int ldb, long long sBb, long long sBh,
                      const float* __restrict__ bias,
                      bf16* __restrict__ C, int ldc, long long sCb, long long sCh,
                      int M, int N, int K, float scale) {
  __shared__ __align__(16) unsigned short Als[128 * 64];
  __shared__ __align__(16) unsigned short Bls[128 * 64];
  int tid = threadIdx.x;
  int lane = tid & 63, wave = tid >> 6;
  int l15 = lane & 15, quad = lane >> 4;
  int wm = wave & 1, wn = wave >> 1;
  int m0 = blockIdx.y * 128, n0 = blockIdx.x * 128;
  int zb = blockIdx.z >> 3, zh = blockIdx.z & 7;
  const bf16* Ab = A + zb * sAb + zh * sAh;
  const bf16* Bb = Bt + zb * sBb + zh * sBh;
  bf16* Cb = C + zb * sCb + zh * sCh;
  f4v acc[4][4];
#pragma unroll
  for (int i = 0; i < 4; i++)
#pragma unroll
    for (int j = 0; j < 4; j++) acc[i][j] = (f4v){0.f, 0.f, 0.f, 0.f};

  int r0 = tid >> 3;            // base staging row 0..31 (segments +32,+64,+96)
  int c0 = tid & 7;             // global 16B chunk within the 64-col k-tile
  int wcol = ((c0 ^ (r0 & 7)) * 8);   // swizzled LDS col ((r0+32s)&7 == r0&7)
  int gcol = c0 * 8;
  const bf16* Ap[4];
  const bf16* Bp[4];
#pragma unroll
  for (int s = 0; s < 4; s++) {
    Ap[s] = Ab + (size_t)(m0 + r0 + s * 32) * lda + gcol;
    Bp[s] = Bb + (size_t)(n0 + r0 + s * 32) * ldb + gcol;
  }
  uint4 abuf[4], bbuf[4];
#pragma unroll
  for (int s = 0; s < 4; s++) {
    abuf[s] = *(const uint4*)(Ap[s]);
    bbuf[s] = *(const uint4*)(Bp[s]);
  }
  int xr = l15 & 7;
  for (int k0 = 0; k0 < K; k0 += 64) {
#pragma unroll
    for (int s = 0; s < 4; s++) {
      *(uint4*)&Als[(r0 + s * 32) * 64 + wcol] = abuf[s];
      *(uint4*)&Bls[(r0 + s * 32) * 64 + wcol] = bbuf[s];
    }
    __syncthreads();
    int kn = k0 + 64;
    if (kn < K) {            // next-tile loads in flight during ds_read+MFMA
#pragma unroll
      for (int s = 0; s < 4; s++) {
        abuf[s] = *(const uint4*)(Ap[s] + kn);
        bbuf[s] = *(const uint4*)(Bp[s] + kn);
      }
    }
    s8v af[4][2], bfr[4][2];
#pragma unroll
    for (int i = 0; i < 4; i++) {
      int rb = (wm * 64 + i * 16 + l15) * 64;
      af[i][0] = *(const s8v*)&Als[rb + ((quad ^ xr) * 8)];
      af[i][1] = *(const s8v*)&Als[rb + (((4 + quad) ^ xr) * 8)];
    }
#pragma unroll
    for (int j = 0; j < 4; j++) {
      int rb = (wn * 64 + j * 16 + l15) * 64;
      bfr[j][0] = *(const s8v*)&Bls[rb + ((quad ^ xr) * 8)];
      bfr[j][1] = *(const s8v*)&Bls[rb + (((4 + quad) ^ xr) * 8)];
    }
#pragma unroll
    for (int i = 0; i < 4; i++)
#pragma unroll
      for (int j = 0; j < 4; j++) {
        acc[i][j] = __builtin_amdgcn_mfma_f32_16x16x32_bf16(af[i][0], bfr[j][0], acc[i][j], 0, 0, 0);
        acc[i][j] = __builtin_amdgcn_mfma_f32_16x16x32_bf16(af[i][1], bfr[j][1], acc[i][j], 0, 0, 0);
      }
    __syncthreads();
  }
#pragma unroll
  for (int i = 0; i < 4; i++) {
#pragma unroll
    for (int j = 0; j < 4; j++) {
      int n = n0 + wn * 64 + j * 16 + l15;
      float bval = bias ? bias[n] : 0.f;
#pragma unroll
      for (int r = 0; r < 4; r++) {
        int m = m0 + wm * 64 + i * 16 + quad * 4 + r;
        float v = (acc[i][j][r] + bval) * scale;
        if (GELU) v = 0.5f * v * (1.f + erff(v * 0.70710678118654752f));
        Cb[(size_t)m * ldc + n] = f2bf(v);
      }
    }
  }
}

// ---- Fused attention: QK^T -> softmax -> PV, P kept in LDS (unchanged R16) ----
__global__ __launch_bounds__(256)
void fused_attn_kernel(const bf16* __restrict__ qkv, const bf16* __restrict__ vt,
                       bf16* __restrict__ ctx) {
  __shared__ __align__(16) unsigned short Qs[32 * 136];
  __shared__ __align__(16) unsigned short St[128 * 40];
  __shared__ __align__(16) unsigned short P[32 * 520];
  __shared__ float invs[32];
  const float QSCALE = 0.08838834764831845f;  // 1/sqrt(128)
  int tid = threadIdx.x;
  int lane = tid & 63, wave = tid >> 6;
  int l15 = lane & 15, quad = lane >> 4;
  int wm = wave & 1, wn = wave >> 1;          // 2x2 wave grid
  int qt = blockIdx.x;                         // 0..15
  int bh = blockIdx.y;                         // 0..127
  int b = bh >> 3, hd = bh & 7;
  size_t rowQ = (size_t)b * SS + qt * 32;      // token row of q-row 0

  // phase 1: Q (32x128) -> Qs
  {
    int r = tid >> 4, ck = (tid & 15) * 8;     // 16 chunks of 8 ushorts/row
    *(uint4*)&Qs[r * 136 + ck] =
        *(const uint4*)(qkv + (rowQ + r) * (3 * HH) + hd * HDD + ck);
    *(uint4*)&Qs[(r + 16) * 136 + ck] =
        *(const uint4*)(qkv + (rowQ + r + 16) * (3 * HH) + hd * HDD + ck);
  }

  int r0 = tid >> 2;           // staging row 0..63 (and +64)
  int q8 = (tid & 3) * 8;
  f4v acc[4];
#pragma unroll
  for (int j = 0; j < 4; j++) acc[j] = (f4v){0.f, 0.f, 0.f, 0.f};

  // phase 2: QK^T -> P.  K source row = b*512 + nt*128 + row, col = HH+hd*128+kt*32
#define KSRC(tt, rr) (qkv + ((size_t)b * SS + ((tt) >> 2) * 128 + (rr)) * (3 * HH) \
                          + HH + hd * HDD + ((tt) & 3) * 32 + q8)
  uint4 ka = *(const uint4*)KSRC(0, r0);
  uint4 kb = *(const uint4*)KSRC(0, r0 + 64);
  for (int tt = 0; tt < 16; ++tt) {
    *(uint4*)&St[r0 * 40 + q8] = ka;
    *(uint4*)&St[(r0 + 64) * 40 + q8] = kb;
    __syncthreads();
    if (tt < 15) {
      ka = *(const uint4*)KSRC(tt + 1, r0);
      kb = *(const uint4*)KSRC(tt + 1, r0 + 64);
    }
    int kt = tt & 3;
    s8v af = *(const s8v*)&Qs[(wm * 16 + l15) * 136 + kt * 32 + quad * 8];
    s8v bfr[4];
#pragma unroll
    for (int j = 0; j < 4; j++)
      bfr[j] = *(const s8v*)&St[(wn * 64 + j * 16 + l15) * 40 + quad * 8];
#pragma unroll
    for (int j = 0; j < 4; j++)
      acc[j] = __builtin_amdgcn_mfma_f32_16x16x32_bf16(af, bfr[j], acc[j], 0, 0, 0);
    __syncthreads();
    if (kt == 3) {               // tile of 128 key-cols done -> write P, reset
      int nt = tt >> 2;
#pragma unroll
      for (int j = 0; j < 4; j++)
#pragma unroll
        for (int r = 0; r < 4; r++)
          P[(wm * 16 + quad * 4 + r) * 520 + nt * 128 + wn * 64 + j * 16 + l15] =
              (unsigned short)__bfloat16_as_ushort(f2bf(acc[j][r] * QSCALE));
#pragma unroll
      for (int j = 0; j < 4; j++) acc[j] = (f4v){0.f, 0.f, 0.f, 0.f};
    }
  }
#undef KSRC

  // phase 3: softmax over P rows (512), 8 threads/row
  __syncthreads();
  {
    int row = tid >> 3, sub = tid & 7;
    uint4* pp = (uint4*)&P[row * 520 + sub * 64];
    float mx = -1e30f;
#pragma unroll
    for (int c = 0; c < 8; c++) {
      union { uint4 u4; unsigned short u[8]; } w; w.u4 = pp[c];
#pragma unroll
      for (int e = 0; e < 8; e++) mx = fmaxf(mx, us2f(w.u[e]));
    }
    mx = fmaxf(mx, __shfl_xor(mx, 1));
    mx = fmaxf(mx, __shfl_xor(mx, 2));
    mx = fmaxf(mx, __shfl_xor(mx, 4));
    float sum = 0.f;
#pragma unroll
    for (int c = 0; c < 8; c++) {
      union { uint4 u4; unsigned short u[8]; } w; w.u4 = pp[c];
#pragma unroll
      for (int e = 0; e < 8; e++) {
        float f = __expf(us2f(w.u[e]) - mx);
        sum += f;
        bf16 bb = f2bf(f);
        w.u[e] = *(unsigned short*)&bb;
      }
      pp[c] = w.u4;
    }
    sum += __shfl_xor(sum, 1);
    sum += __shfl_xor(sum, 2);
    sum += __shfl_xor(sum, 4);
    if (sub == 0) invs[row] = 1.f / sum;
  }

  // phase 4: PV.  ctx[32][128] = P[32][512] @ vt[bh]^T, 16 k-steps of 32 keys
  const bf16* vb = vt + (size_t)bh * HDD * SS;
  uint4 va0 = *(const uint4*)(vb + (size_t)r0 * SS + q8);
  uint4 va1 = *(const uint4*)(vb + (size_t)(r0 + 64) * SS + q8);
  for (int kt = 0; kt < 16; ++kt) {
    *(uint4*)&St[r0 * 40 + q8] = va0;
    *(uint4*)&St[(r0 + 64) * 40 + q8] = va1;
    __syncthreads();
    if (kt < 15) {
      va0 = *(const uint4*)(vb + (size_t)r0 * SS + (kt + 1) * 32 + q8);
      va1 = *(const uint4*)(vb + (size_t)(r0 + 64) * SS + (kt + 1) * 32 + q8);
    }
    s8v af = *(const s8v*)&P[(wm * 16 + l15) * 520 + kt * 32 + quad * 8];
    s8v bfr[4];
#pragma unroll
    for (int j = 0; j < 4; j++)
      bfr[j] = *(const s8v*)&St[(wn * 64 + j * 16 + l15) * 40 + quad * 8];
#pragma unroll
    for (int j = 0; j < 4; j++)
      acc[j] = __builtin_amdgcn_mfma_f32_16x16x32_bf16(af, bfr[j], acc[j], 0, 0, 0);
    __syncthreads();
  }
  // epilogue: scale by 1/rowsum, write ctx[token][hd*128 + d]
#pragma unroll
  for (int j = 0; j < 4; j++) {
#pragma unroll
    for (int r = 0; r < 4; r++) {
      int rl = wm * 16 + quad * 4 + r;
      int d = wn * 64 + j * 16 + l15;
      ctx[(rowQ + rl) * HH + hd * HDD + d] = f2bf(acc[j][r] * invs[rl]);
    }
  }
}

// ---------------- launch ----------------
extern "C" void kernel_launch(void* const* d_in, const int* in_sizes, int n_in,
                              void* d_out, int out_size, void* d_ws, size_t ws_size,
                              hipStream_t stream) {
  const float* x     = (const float*)d_in[0];
  const float* pos   = (const float*)d_in[1];
  const float* eg    = (const float*)d_in[2];
  const float* ebeta = (const float*)d_in[3];
  const float* Wq    = (const float*)d_in[4];
  const float* Wk    = (const float*)d_in[5];
  const float* Wv    = (const float*)d_in[6];
  const float* qbias = (const float*)d_in[7];
  const float* vbias = (const float*)d_in[8];
  const float* Wo    = (const float*)d_in[9];
  const float* bo    = (const float*)d_in[10];
  const float* l1g   = (const float*)d_in[11];
  const float* l1b   = (const float*)d_in[12];
  const float* Wi    = (const float*)d_in[13];
  const float* bi    = (const float*)d_in[14];
  const float* Wf    = (const float*)d_in[15];
  const float* bfb   = (const float*)d_in[16];
  const float* l2g   = (const float*)d_in[17];
  const float* l2b   = (const float*)d_in[18];

  // --- workspace (256 MiB): [MiB offsets] ---
  char* w = (char*)d_ws;
  const size_t MB = (size_t)1 << 20;
  bf16* h      = (bf16*)(w + 0 * MB);     // 16
  bf16* qkv    = (bf16*)(w + 16 * MB);    // 48: [T][3H] fused q|k|v
  bf16* ctx    = (bf16*)(w + 64 * MB);    // 16
  bf16* tmp1   = (bf16*)(w + 80 * MB);    // 16
  bf16* attn   = (bf16*)(w + 96 * MB);    // 16
  bf16* ff     = (bf16*)(w + 112 * MB);   // 48
  bf16* tmp2   = (bf16*)(w + 176 * MB);   // 16
  bf16* vt     = (bf16*)(w + 192 * MB);   // 16
  bf16* Wqkvt  = (bf16*)(w + 208 * MB);   // 6: [3H][H] packed q|k|v rows
  bf16* Wot    = (bf16*)(w + 214 * MB);   // 2
  bf16* Wit    = (bf16*)(w + 216 * MB);   // 6
  bf16* Wft    = (bf16*)(w + 222 * MB);   // 6
  float* qkvb  = (float*)(w + 228 * MB);  // 12 KB
  float* out   = (float*)d_out;

  embed_ln_kernel<<<TT, 256, 0, stream>>>(x, pos, eg, ebeta, h);

  convert_w_kernel<<<dim3(HH / 32, HH / 32), 256, 0, stream>>>(Wq, Wqkvt, HH, HH);
  convert_w_kernel<<<dim3(HH / 32, HH / 32), 256, 0, stream>>>(Wk, Wqkvt + (size_t)HH * HH, HH, HH);
  convert_w_kernel<<<dim3(HH / 32, HH / 32), 256, 0, stream>>>(Wv, Wqkvt + (size_t)2 * HH * HH, HH, HH);
  convert_w_kernel<<<dim3(HH / 32, HH / 32), 256, 0, stream>>>(Wo, Wot, HH, HH);
  convert_w_kernel<<<dim3(FFF / 32, HH / 32), 256, 0, stream>>>(Wi, Wit, HH, FFF);
  convert_w_kernel<<<dim3(HH / 32, FFF / 32), 256, 0, stream>>>(Wf, Wft, FFF, HH);
  build_qkv_bias_kernel<<<12, 256, 0, stream>>>(qbias, vbias, qkvb);

  // fused QKV: qkv[8192,3072] = h @ Wqkvt^T + qkvb
  mfma_gemm_kernel<0><<<dim3(24, 64, 1), 256, 0, stream>>>(
      h, HH, 0, 0, Wqkvt, HH, 0, 0, qkvb, qkv, 3 * HH, 0, 0, TT, 3 * HH, HH, 1.f);

  transpose_v_kernel<<<dim3(SS / 32, HDD / 32, BB * NHH), 256, 0, stream>>>(qkv + 2 * HH, vt);

  // fused attention: QK^T + softmax + PV (no score materialization)
  fused_attn_kernel<<<dim3(SS / 32, BB * NHH), 256, 0, stream>>>(qkv, vt, ctx);

  mfma_gemm_kernel<0><<<dim3(8, 64, 1), 256, 0, stream>>>(
      ctx, HH, 0, 0, Wot, HH, 0, 0, bo, tmp1, HH, 0, 0, TT, HH, HH, 1.f);
  add_ln_kernel<0><<<TT, 256, 0, stream>>>(tmp1, h, l1g, l1b, attn);

  mfma_gemm_kernel<1><<<dim3(24, 64, 1), 256, 0, stream>>>(
      attn, HH, 0, 0, Wit, HH, 0, 0, bi, ff, FFF, 0, 0, TT, FFF, HH, 1.f);
  mfma_gemm_kernel<0><<<dim3(8, 64, 1), 256, 0, stream>>>(
      ff, FFF, 0, 0, Wft, FFF, 0, 0, bfb, tmp2, HH, 0, 0, TT, HH, FFF, 1.f);
  add_ln_kernel<1><<<TT, 256, 0, stream>>>(tmp2, attn, l2g, l2b, out);
}

// Round 10
// 1032.252 us; speedup vs baseline: 1.0039x; 1.0039x over previous
//
#include <hip/hip_runtime.h>
#include <hip/hip_bf16.h>

// DeBERTa layer: B=16,S=512,H=1024,NH=8,HD=128,FF=3072.
// R18 = R17 with the spill fixed: BK=64 kept, but the two k-subtiles are
// processed SEQUENTIALLY (af[4]+bfr[4] live at a time, not af[4][2]) so the
// prefetch buffers stay in registers (R17: 790MB scratch WRITE_SIZE).
// Fused attention and all other kernels unchanged.
#define BB  16
#define SS  512
#define HH  1024
#define NHH 8
#define HDD 128
#define FFF 3072
#define TT  (BB * SS)   // 8192 tokens

typedef __hip_bfloat16 bf16;
typedef short s8v __attribute__((ext_vector_type(8)));   // 8 bf16 bits (4 VGPRs)
typedef float f4v __attribute__((ext_vector_type(4)));   // 4 f32 acc

__device__ __forceinline__ float bf2f(bf16 v) { return __bfloat162float(v); }
__device__ __forceinline__ bf16 f2bf(float f) { return __float2bfloat16(f); }
__device__ __forceinline__ float us2f(unsigned short u) {
  union { unsigned int i; float f; } c; c.i = (unsigned int)u << 16; return c.f;
}

// ---------------- Embedding LayerNorm (f32 in -> bf16 out) ----------------------
__global__ void embed_ln_kernel(const float* __restrict__ x, const float* __restrict__ pos,
                                const float* __restrict__ g, const float* __restrict__ bta,
                                bf16* __restrict__ h) {
  int t = blockIdx.x;
  int s = t & (SS - 1);
  int tid = threadIdx.x;
  const float* xr = x + (size_t)t * HH;
  const float* pr = pos + (size_t)s * HH;
  float vals[4];
  float sum = 0.f;
#pragma unroll
  for (int i = 0; i < 4; i++) {
    int c = tid + i * 256;
    vals[i] = xr[c] + pr[c];
    sum += vals[i];
  }
  __shared__ float red[4];
#pragma unroll
  for (int off = 32; off > 0; off >>= 1) sum += __shfl_down(sum, off, 64);
  if ((tid & 63) == 0) red[tid >> 6] = sum;
  __syncthreads();
  float mean = (red[0] + red[1] + red[2] + red[3]) * (1.f / HH);
  float vsum = 0.f;
#pragma unroll
  for (int i = 0; i < 4; i++) { float d = vals[i] - mean; vsum += d * d; }
  __syncthreads();
#pragma unroll
  for (int off = 32; off > 0; off >>= 1) vsum += __shfl_down(vsum, off, 64);
  if ((tid & 63) == 0) red[tid >> 6] = vsum;
  __syncthreads();
  float rstd = rsqrtf((red[0] + red[1] + red[2] + red[3]) * (1.f / HH) + 1e-7f);
  bf16* hr = h + (size_t)t * HH;
#pragma unroll
  for (int i = 0; i < 4; i++) {
    int c = tid + i * 256;
    hr[c] = f2bf((vals[i] - mean) * rstd * g[c] + bta[c]);
  }
}

// ------- a(bf16)+res(bf16) -> LN -> out (OUT_F32 ? float : bf16) ---------------
template <int OUT_F32>
__global__ void add_ln_kernel(const bf16* __restrict__ a, const bf16* __restrict__ res,
                              const float* __restrict__ g, const float* __restrict__ bta,
                              void* __restrict__ outv) {
  int t = blockIdx.x;
  int tid = threadIdx.x;
  const bf16* ar = a + (size_t)t * HH;
  const bf16* rr = res + (size_t)t * HH;
  float vals[4];
  float sum = 0.f;
#pragma unroll
  for (int i = 0; i < 4; i++) {
    int c = tid + i * 256;
    vals[i] = bf2f(ar[c]) + bf2f(rr[c]);
    sum += vals[i];
  }
  __shared__ float red[4];
#pragma unroll
  for (int off = 32; off > 0; off >>= 1) sum += __shfl_down(sum, off, 64);
  if ((tid & 63) == 0) red[tid >> 6] = sum;
  __syncthreads();
  float mean = (red[0] + red[1] + red[2] + red[3]) * (1.f / HH);
  float vsum = 0.f;
#pragma unroll
  for (int i = 0; i < 4; i++) { float d = vals[i] - mean; vsum += d * d; }
  __syncthreads();
#pragma unroll
  for (int off = 32; off > 0; off >>= 1) vsum += __shfl_down(vsum, off, 64);
  if ((tid & 63) == 0) red[tid >> 6] = vsum;
  __syncthreads();
  float rstd = rsqrtf((red[0] + red[1] + red[2] + red[3]) * (1.f / HH) + 1e-7f);
#pragma unroll
  for (int i = 0; i < 4; i++) {
    int c = tid + i * 256;
    float o = (vals[i] - mean) * rstd * g[c] + bta[c];
    if (OUT_F32)
      ((float*)outv)[(size_t)t * HH + c] = o;
    else
      ((bf16*)outv)[(size_t)t * HH + c] = f2bf(o);
  }
}

// ---- weight convert+transpose: W[K,N] f32 -> Wt[N,K] bf16 (K fixed per call) --
__global__ void convert_w_kernel(const float* __restrict__ W, bf16* __restrict__ Wt,
                                 int K, int N) {
  __shared__ float tile[32][33];
  int n0 = blockIdx.x * 32, k0 = blockIdx.y * 32;
#pragma unroll
  for (int it = 0; it < 4; it++) {
    int idx = threadIdx.x + it * 256;
    int ty = idx >> 5, tx = idx & 31;
    tile[ty][tx] = W[(size_t)(k0 + ty) * N + n0 + tx];
  }
  __syncthreads();
#pragma unroll
  for (int it = 0; it < 4; it++) {
    int idx = threadIdx.x + it * 256;
    int ty = idx >> 5, tx = idx & 31;
    Wt[(size_t)(n0 + ty) * K + k0 + tx] = f2bf(tile[tx][ty]);
  }
}

// ---- concat qkv bias: [qbias | 0 | vbias] (f32) -------------------------------
__global__ void build_qkv_bias_kernel(const float* __restrict__ qb,
                                      const float* __restrict__ vb,
                                      float* __restrict__ o) {
  int i = blockIdx.x * 256 + threadIdx.x;  // 0..3071
  float v = 0.f;
  if (i < HH) v = qb[i];
  else if (i >= 2 * HH) v = vb[i - 2 * HH];
  o[i] = v;
}

// ---- V transpose per head: qkv v-cols -> vt[b,h,dim,key] (bf16) ---------------
__global__ void transpose_v_kernel(const bf16* __restrict__ v, bf16* __restrict__ vt) {
  __shared__ unsigned short tile[32][33];
  int bh = blockIdx.z;
  int s0 = blockIdx.x * 32, d0 = blockIdx.y * 32;
  int b = bh >> 3, hd = bh & 7;
  const unsigned short* vp = (const unsigned short*)v + ((size_t)b * SS) * (3 * HH) + hd * HDD;
  unsigned short* vtp = (unsigned short*)vt + (size_t)bh * HDD * SS;
#pragma unroll
  for (int it = 0; it < 4; it++) {
    int idx = threadIdx.x + it * 256;
    int ty = idx >> 5, tx = idx & 31;
    tile[ty][tx] = vp[(size_t)(s0 + ty) * (3 * HH) + d0 + tx];
  }
  __syncthreads();
#pragma unroll
  for (int it = 0; it < 4; it++) {
    int idx = threadIdx.x + it * 256;
    int ty = idx >> 5, tx = idx & 31;
    vtp[(size_t)(d0 + ty) * SS + s0 + tx] = tile[tx][ty];
  }
}

// ---- 128x128 MFMA GEMM, BK=64, sequential k-subtiles (no spill) ---------------
// C = act((A @ Bt^T + bias)*scale). 4 waves x 4x4 16x16x32 MFMA, 32 MFMA per
// barrier-pair. LDS [128][64] ushorts/operand. Chunk c of row r stored at
// c ^ (r&7) (write: global col permuted; read: XOR with l15&7) -> uniform
// 8-slot spread. Fragments for the two k-subtiles are read+consumed
// SEQUENTIALLY so only af[4]+bfr[4] (32 VGPRs) are live alongside the
// 8-uint4 prefetch (R17 kept 64 live -> spilled 790MB to scratch).
template <int GELU>
__global__ __launch_bounds__(256)
void mfma_gemm_kernel(const bf16* __restrict__ A, int lda, long long sAb, long long sAh,
                      const bf16* __restrict__ Bt, int ldb, long long sBb, long long sBh,
                      const float* __restrict__ bias,
                      bf16* __restrict__ C, int ldc, long long sCb, long long sCh,
                      int M, int N, int K, float scale) {
  __shared__ __align__(16) unsigned short Als[128 * 64];
  __shared__ __align__(16) unsigned short Bls[128 * 64];
  int tid = threadIdx.x;
  int lane = tid & 63, wave = tid >> 6;
  int l15 = lane & 15, quad = lane >> 4;
  int wm = wave & 1, wn = wave >> 1;
  int m0 = blockIdx.y * 128, n0 = blockIdx.x * 128;
  int zb = blockIdx.z >> 3, zh = blockIdx.z & 7;
  const bf16* Ab = A + zb * sAb + zh * sAh;
  const bf16* Bb = Bt + zb * sBb + zh * sBh;
  bf16* Cb = C + zb * sCb + zh * sCh;
  f4v acc[4][4];
#pragma unroll
  for (int i = 0; i < 4; i++)
#pragma unroll
    for (int j = 0; j < 4; j++) acc[i][j] = (f4v){0.f, 0.f, 0.f, 0.f};

  int r0 = tid >> 3;            // base staging row 0..31 (segments +32,+64,+96)
  int c0 = tid & 7;             // global 16B chunk within the 64-col k-tile
  int wcol = ((c0 ^ (r0 & 7)) * 8);   // swizzled LDS col ((r0+32s)&7 == r0&7)
  // two base pointers; segment offsets computed (s*32*ld) to save VGPRs
  const bf16* Apb = Ab + (size_t)(m0 + r0) * lda + c0 * 8;
  const bf16* Bpb = Bb + (size_t)(n0 + r0) * ldb + c0 * 8;
  uint4 abuf[4], bbuf[4];
#pragma unroll
  for (int s = 0; s < 4; s++) {
    abuf[s] = *(const uint4*)(Apb + (size_t)(s * 32) * lda);
    bbuf[s] = *(const uint4*)(Bpb + (size_t)(s * 32) * ldb);
  }
  int xr = l15 & 7;
  for (int k0 = 0; k0 < K; k0 += 64) {
#pragma unroll
    for (int s = 0; s < 4; s++) {
      *(uint4*)&Als[(r0 + s * 32) * 64 + wcol] = abuf[s];
      *(uint4*)&Bls[(r0 + s * 32) * 64 + wcol] = bbuf[s];
    }
    __syncthreads();
    int kn = k0 + 64;
    if (kn < K) {            // next-tile loads in flight during ds_read+MFMA
#pragma unroll
      for (int s = 0; s < 4; s++) {
        abuf[s] = *(const uint4*)(Apb + (size_t)(s * 32) * lda + kn);
        bbuf[s] = *(const uint4*)(Bpb + (size_t)(s * 32) * ldb + kn);
      }
    }
    // k-subtile 0
    {
      s8v af[4], bfr[4];
#pragma unroll
      for (int i = 0; i < 4; i++)
        af[i] = *(const s8v*)&Als[(wm * 64 + i * 16 + l15) * 64 + ((quad ^ xr) * 8)];
#pragma unroll
      for (int j = 0; j < 4; j++)
        bfr[j] = *(const s8v*)&Bls[(wn * 64 + j * 16 + l15) * 64 + ((quad ^ xr) * 8)];
#pragma unroll
      for (int i = 0; i < 4; i++)
#pragma unroll
        for (int j = 0; j < 4; j++)
          acc[i][j] = __builtin_amdgcn_mfma_f32_16x16x32_bf16(af[i], bfr[j], acc[i][j], 0, 0, 0);
    }
    // k-subtile 1
    {
      s8v af[4], bfr[4];
#pragma unroll
      for (int i = 0; i < 4; i++)
        af[i] = *(const s8v*)&Als[(wm * 64 + i * 16 + l15) * 64 + (((4 + quad) ^ xr) * 8)];
#pragma unroll
      for (int j = 0; j < 4; j++)
        bfr[j] = *(const s8v*)&Bls[(wn * 64 + j * 16 + l15) * 64 + (((4 + quad) ^ xr) * 8)];
#pragma unroll
      for (int i = 0; i < 4; i++)
#pragma unroll
        for (int j = 0; j < 4; j++)
          acc[i][j] = __builtin_amdgcn_mfma_f32_16x16x32_bf16(af[i], bfr[j], acc[i][j], 0, 0, 0);
    }
    __syncthreads();
  }
#pragma unroll
  for (int i = 0; i < 4; i++) {
#pragma unroll
    for (int j = 0; j < 4; j++) {
      int n = n0 + wn * 64 + j * 16 + l15;
      float bval = bias ? bias[n] : 0.f;
#pragma unroll
      for (int r = 0; r < 4; r++) {
        int m = m0 + wm * 64 + i * 16 + quad * 4 + r;
        float v = (acc[i][j][r] + bval) * scale;
        if (GELU) v = 0.5f * v * (1.f + erff(v * 0.70710678118654752f));
        Cb[(size_t)m * ldc + n] = f2bf(v);
      }
    }
  }
}

// ---- Fused attention: QK^T -> softmax -> PV, P kept in LDS (unchanged R16) ----
__global__ __launch_bounds__(256)
void fused_attn_kernel(const bf16* __restrict__ qkv, const bf16* __restrict__ vt,
                       bf16* __restrict__ ctx) {
  __shared__ __align__(16) unsigned short Qs[32 * 136];
  __shared__ __align__(16) unsigned short St[128 * 40];
  __shared__ __align__(16) unsigned short P[32 * 520];
  __shared__ float invs[32];
  const float QSCALE = 0.08838834764831845f;  // 1/sqrt(128)
  int tid = threadIdx.x;
  int lane = tid & 63, wave = tid >> 6;
  int l15 = lane & 15, quad = lane >> 4;
  int wm = wave & 1, wn = wave >> 1;          // 2x2 wave grid
  int qt = blockIdx.x;                         // 0..15
  int bh = blockIdx.y;                         // 0..127
  int b = bh >> 3, hd = bh & 7;
  size_t rowQ = (size_t)b * SS + qt * 32;      // token row of q-row 0

  // phase 1: Q (32x128) -> Qs
  {
    int r = tid >> 4, ck = (tid & 15) * 8;     // 16 chunks of 8 ushorts/row
    *(uint4*)&Qs[r * 136 + ck] =
        *(const uint4*)(qkv + (rowQ + r) * (3 * HH) + hd * HDD + ck);
    *(uint4*)&Qs[(r + 16) * 136 + ck] =
        *(const uint4*)(qkv + (rowQ + r + 16) * (3 * HH) + hd * HDD + ck);
  }

  int r0 = tid >> 2;           // staging row 0..63 (and +64)
  int q8 = (tid & 3) * 8;
  f4v acc[4];
#pragma unroll
  for (int j = 0; j < 4; j++) acc[j] = (f4v){0.f, 0.f, 0.f, 0.f};

  // phase 2: QK^T -> P.  K source row = b*512 + nt*128 + row, col = HH+hd*128+kt*32
#define KSRC(tt, rr) (qkv + ((size_t)b * SS + ((tt) >> 2) * 128 + (rr)) * (3 * HH) \
                          + HH + hd * HDD + ((tt) & 3) * 32 + q8)
  uint4 ka = *(const uint4*)KSRC(0, r0);
  uint4 kb = *(const uint4*)KSRC(0, r0 + 64);
  for (int tt = 0; tt < 16; ++tt) {
    *(uint4*)&St[r0 * 40 + q8] = ka;
    *(uint4*)&St[(r0 + 64) * 40 + q8] = kb;
    __syncthreads();
    if (tt < 15) {
      ka = *(const uint4*)KSRC(tt + 1, r0);
      kb = *(const uint4*)KSRC(tt + 1, r0 + 64);
    }
    int kt = tt & 3;
    s8v af = *(const s8v*)&Qs[(wm * 16 + l15) * 136 + kt * 32 + quad * 8];
    s8v bfr[4];
#pragma unroll
    for (int j = 0; j < 4; j++)
      bfr[j] = *(const s8v*)&St[(wn * 64 + j * 16 + l15) * 40 + quad * 8];
#pragma unroll
    for (int j = 0; j < 4; j++)
      acc[j] = __builtin_amdgcn_mfma_f32_16x16x32_bf16(af, bfr[j], acc[j], 0, 0, 0);
    __syncthreads();
    if (kt == 3) {               // tile of 128 key-cols done -> write P, reset
      int nt = tt >> 2;
#pragma unroll
      for (int j = 0; j < 4; j++)
#pragma unroll
        for (int r = 0; r < 4; r++)
          P[(wm * 16 + quad * 4 + r) * 520 + nt * 128 + wn * 64 + j * 16 + l15] =
              (unsigned short)__bfloat16_as_ushort(f2bf(acc[j][r] * QSCALE));
#pragma unroll
      for (int j = 0; j < 4; j++) acc[j] = (f4v){0.f, 0.f, 0.f, 0.f};
    }
  }
#undef KSRC

  // phase 3: softmax over P rows (512), 8 threads/row
  __syncthreads();
  {
    int row = tid >> 3, sub = tid & 7;
    uint4* pp = (uint4*)&P[row * 520 + sub * 64];
    float mx = -1e30f;
#pragma unroll
    for (int c = 0; c < 8; c++) {
      union { uint4 u4; unsigned short u[8]; } w; w.u4 = pp[c];
#pragma unroll
      for (int e = 0; e < 8; e++) mx = fmaxf(mx, us2f(w.u[e]));
    }
    mx = fmaxf(mx, __shfl_xor(mx, 1));
    mx = fmaxf(mx, __shfl_xor(mx, 2));
    mx = fmaxf(mx, __shfl_xor(mx, 4));
    float sum = 0.f;
#pragma unroll
    for (int c = 0; c < 8; c++) {
      union { uint4 u4; unsigned short u[8]; } w; w.u4 = pp[c];
#pragma unroll
      for (int e = 0; e < 8; e++) {
        float f = __expf(us2f(w.u[e]) - mx);
        sum += f;
        bf16 bb = f2bf(f);
        w.u[e] = *(unsigned short*)&bb;
      }
      pp[c] = w.u4;
    }
    sum += __shfl_xor(sum, 1);
    sum += __shfl_xor(sum, 2);
    sum += __shfl_xor(sum, 4);
    if (sub == 0) invs[row] = 1.f / sum;
  }

  // phase 4: PV.  ctx[32][128] = P[32][512] @ vt[bh]^T, 16 k-steps of 32 keys
  const bf16* vb = vt + (size_t)bh * HDD * SS;
  uint4 va0 = *(const uint4*)(vb + (size_t)r0 * SS + q8);
  uint4 va1 = *(const uint4*)(vb + (size_t)(r0 + 64) * SS + q8);
  for (int kt = 0; kt < 16; ++kt) {
    *(uint4*)&St[r0 * 40 + q8] = va0;
    *(uint4*)&St[(r0 + 64) * 40 + q8] = va1;
    __syncthreads();
    if (kt < 15) {
      va0 = *(const uint4*)(vb + (size_t)r0 * SS + (kt + 1) * 32 + q8);
      va1 = *(const uint4*)(vb + (size_t)(r0 + 64) * SS + (kt + 1) * 32 + q8);
    }
    s8v af = *(const s8v*)&P[(wm * 16 + l15) * 520 + kt * 32 + quad * 8];
    s8v bfr[4];
#pragma unroll
    for (int j = 0; j < 4; j++)
      bfr[j] = *(const s8v*)&St[(wn * 64 + j * 16 + l15) * 40 + quad * 8];
#pragma unroll
    for (int j = 0; j < 4; j++)
      acc[j] = __builtin_amdgcn_mfma_f32_16x16x32_bf16(af, bfr[j], acc[j], 0, 0, 0);
    __syncthreads();
  }
  // epilogue: scale by 1/rowsum, write ctx[token][hd*128 + d]
#pragma unroll
  for (int j = 0; j < 4; j++) {
#pragma unroll
    for (int r = 0; r < 4; r++) {
      int rl = wm * 16 + quad * 4 + r;
      int d = wn * 64 + j * 16 + l15;
      ctx[(rowQ + rl) * HH + hd * HDD + d] = f2bf(acc[j][r] * invs[rl]);
    }
  }
}

// ---------------- launch ----------------
extern "C" void kernel_launch(void* const* d_in, const int* in_sizes, int n_in,
                              void* d_out, int out_size, void* d_ws, size_t ws_size,
                              hipStream_t stream) {
  const float* x     = (const float*)d_in[0];
  const float* pos   = (const float*)d_in[1];
  const float* eg    = (const float*)d_in[2];
  const float* ebeta = (const float*)d_in[3];
  const float* Wq    = (const float*)d_in[4];
  const float* Wk    = (const float*)d_in[5];
  const float* Wv    = (const float*)d_in[6];
  const float* qbias = (const float*)d_in[7];
  const float* vbias = (const float*)d_in[8];
  const float* Wo    = (const float*)d_in[9];
  const float* bo    = (const float*)d_in[10];
  const float* l1g   = (const float*)d_in[11];
  const float* l1b   = (const float*)d_in[12];
  const float* Wi    = (const float*)d_in[13];
  const float* bi    = (const float*)d_in[14];
  const float* Wf    = (const float*)d_in[15];
  const float* bfb   = (const float*)d_in[16];
  const float* l2g   = (const float*)d_in[17];
  const float* l2b   = (const float*)d_in[18];

  // --- workspace (256 MiB): [MiB offsets] ---
  char* w = (char*)d_ws;
  const size_t MB = (size_t)1 << 20;
  bf16* h      = (bf16*)(w + 0 * MB);     // 16
  bf16* qkv    = (bf16*)(w + 16 * MB);    // 48: [T][3H] fused q|k|v
  bf16* ctx    = (bf16*)(w + 64 * MB);    // 16
  bf16* tmp1   = (bf16*)(w + 80 * MB);    // 16
  bf16* attn   = (bf16*)(w + 96 * MB);    // 16
  bf16* ff     = (bf16*)(w + 112 * MB);   // 48
  bf16* tmp2   = (bf16*)(w + 176 * MB);   // 16
  bf16* vt     = (bf16*)(w + 192 * MB);   // 16
  bf16* Wqkvt  = (bf16*)(w + 208 * MB);   // 6: [3H][H] packed q|k|v rows
  bf16* Wot    = (bf16*)(w + 214 * MB);   // 2
  bf16* Wit    = (bf16*)(w + 216 * MB);   // 6
  bf16* Wft    = (bf16*)(w + 222 * MB);   // 6
  float* qkvb  = (float*)(w + 228 * MB);  // 12 KB
  float* out   = (float*)d_out;

  embed_ln_kernel<<<TT, 256, 0, stream>>>(x, pos, eg, ebeta, h);

  convert_w_kernel<<<dim3(HH / 32, HH / 32), 256, 0, stream>>>(Wq, Wqkvt, HH, HH);
  convert_w_kernel<<<dim3(HH / 32, HH / 32), 256, 0, stream>>>(Wk, Wqkvt + (size_t)HH * HH, HH, HH);
  convert_w_kernel<<<dim3(HH / 32, HH / 32), 256, 0, stream>>>(Wv, Wqkvt + (size_t)2 * HH * HH, HH, HH);
  convert_w_kernel<<<dim3(HH / 32, HH / 32), 256, 0, stream>>>(Wo, Wot, HH, HH);
  convert_w_kernel<<<dim3(FFF / 32, HH / 32), 256, 0, stream>>>(Wi, Wit, HH, FFF);
  convert_w_kernel<<<dim3(HH / 32, FFF / 32), 256, 0, stream>>>(Wf, Wft, FFF, HH);
  build_qkv_bias_kernel<<<12, 256, 0, stream>>>(qbias, vbias, qkvb);

  // fused QKV: qkv[8192,3072] = h @ Wqkvt^T + qkvb
  mfma_gemm_kernel<0><<<dim3(24, 64, 1), 256, 0, stream>>>(
      h, HH, 0, 0, Wqkvt, HH, 0, 0, qkvb, qkv, 3 * HH, 0, 0, TT, 3 * HH, HH, 1.f);

  transpose_v_kernel<<<dim3(SS / 32, HDD / 32, BB * NHH), 256, 0, stream>>>(qkv + 2 * HH, vt);

  // fused attention: QK^T + softmax + PV (no score materialization)
  fused_attn_kernel<<<dim3(SS / 32, BB * NHH), 256, 0, stream>>>(qkv, vt, ctx);

  mfma_gemm_kernel<0><<<dim3(8, 64, 1), 256, 0, stream>>>(
      ctx, HH, 0, 0, Wot, HH, 0, 0, bo, tmp1, HH, 0, 0, TT, HH, HH, 1.f);
  add_ln_kernel<0><<<TT, 256, 0, stream>>>(tmp1, h, l1g, l1b, attn);

  mfma_gemm_kernel<1><<<dim3(24, 64, 1), 256, 0, stream>>>(
      attn, HH, 0, 0, Wit, HH, 0, 0, bi, ff, FFF, 0, 0, TT, FFF, HH, 1.f);
  mfma_gemm_kernel<0><<<dim3(8, 64, 1), 256, 0, stream>>>(
      ff, FFF, 0, 0, Wft, FFF, 0, 0, bfb, tmp2, HH, 0, 0, TT, HH, FFF, 1.f);
  add_ln_kernel<1><<<TT, 256, 0, stream>>>(tmp2, attn, l2g, l2b, out);
}

// Round 11
// 515.485 us; speedup vs baseline: 2.0102x; 2.0025x over previous
//
#include <hip/hip_runtime.h>
#include <hip/hip_bf16.h>

// DeBERTa layer: B=16,S=512,H=1024,NH=8,HD=128,FF=3072.
// R19: consolidation. BK=64 abandoned (R17/R18 both spilled: allocator pins
// 72 arch-VGPRs, prefetch goes to scratch -> 780MB WRITE_SIZE). Best measured
// config restored (R15 structure) with its A/B verdict applied consistently:
// ALL dense GEMMs (QKV/Wo/Wi/Wf) on gemm_dbuf (gload_lds + LDS double-buffer,
// BK=32, 89.0us measured, 0 conflicts, no spill); V1 reg-staging kept only
// for batched QK^T / PV. Separate softmax middle (R15's, best measured).
#define BB  16
#define SS  512
#define HH  1024
#define NHH 8
#define HDD 128
#define FFF 3072
#define TT  (BB * SS)   // 8192 tokens

typedef __hip_bfloat16 bf16;
typedef short s8v __attribute__((ext_vector_type(8)));   // 8 bf16 bits (4 VGPRs)
typedef float f4v __attribute__((ext_vector_type(4)));   // 4 f32 acc

__device__ __forceinline__ float bf2f(bf16 v) { return __bfloat162float(v); }
__device__ __forceinline__ bf16 f2bf(float f) { return __float2bfloat16(f); }
__device__ __forceinline__ float us2f(unsigned short u) {
  union { unsigned int i; float f; } c; c.i = (unsigned int)u << 16; return c.f;
}

// ---------------- Embedding LayerNorm (f32 in -> bf16 out) ----------------------
__global__ void embed_ln_kernel(const float* __restrict__ x, const float* __restrict__ pos,
                                const float* __restrict__ g, const float* __restrict__ bta,
                                bf16* __restrict__ h) {
  int t = blockIdx.x;
  int s = t & (SS - 1);
  int tid = threadIdx.x;
  const float* xr = x + (size_t)t * HH;
  const float* pr = pos + (size_t)s * HH;
  float vals[4];
  float sum = 0.f;
#pragma unroll
  for (int i = 0; i < 4; i++) {
    int c = tid + i * 256;
    vals[i] = xr[c] + pr[c];
    sum += vals[i];
  }
  __shared__ float red[4];
#pragma unroll
  for (int off = 32; off > 0; off >>= 1) sum += __shfl_down(sum, off, 64);
  if ((tid & 63) == 0) red[tid >> 6] = sum;
  __syncthreads();
  float mean = (red[0] + red[1] + red[2] + red[3]) * (1.f / HH);
  float vsum = 0.f;
#pragma unroll
  for (int i = 0; i < 4; i++) { float d = vals[i] - mean; vsum += d * d; }
  __syncthreads();
#pragma unroll
  for (int off = 32; off > 0; off >>= 1) vsum += __shfl_down(vsum, off, 64);
  if ((tid & 63) == 0) red[tid >> 6] = vsum;
  __syncthreads();
  float rstd = rsqrtf((red[0] + red[1] + red[2] + red[3]) * (1.f / HH) + 1e-7f);
  bf16* hr = h + (size_t)t * HH;
#pragma unroll
  for (int i = 0; i < 4; i++) {
    int c = tid + i * 256;
    hr[c] = f2bf((vals[i] - mean) * rstd * g[c] + bta[c]);
  }
}

// ------- a(bf16)+res(bf16) -> LN -> out (OUT_F32 ? float : bf16) ---------------
template <int OUT_F32>
__global__ void add_ln_kernel(const bf16* __restrict__ a, const bf16* __restrict__ res,
                              const float* __restrict__ g, const float* __restrict__ bta,
                              void* __restrict__ outv) {
  int t = blockIdx.x;
  int tid = threadIdx.x;
  const bf16* ar = a + (size_t)t * HH;
  const bf16* rr = res + (size_t)t * HH;
  float vals[4];
  float sum = 0.f;
#pragma unroll
  for (int i = 0; i < 4; i++) {
    int c = tid + i * 256;
    vals[i] = bf2f(ar[c]) + bf2f(rr[c]);
    sum += vals[i];
  }
  __shared__ float red[4];
#pragma unroll
  for (int off = 32; off > 0; off >>= 1) sum += __shfl_down(sum, off, 64);
  if ((tid & 63) == 0) red[tid >> 6] = sum;
  __syncthreads();
  float mean = (red[0] + red[1] + red[2] + red[3]) * (1.f / HH);
  float vsum = 0.f;
#pragma unroll
  for (int i = 0; i < 4; i++) { float d = vals[i] - mean; vsum += d * d; }
  __syncthreads();
#pragma unroll
  for (int off = 32; off > 0; off >>= 1) vsum += __shfl_down(vsum, off, 64);
  if ((tid & 63) == 0) red[tid >> 6] = vsum;
  __syncthreads();
  float rstd = rsqrtf((red[0] + red[1] + red[2] + red[3]) * (1.f / HH) + 1e-7f);
#pragma unroll
  for (int i = 0; i < 4; i++) {
    int c = tid + i * 256;
    float o = (vals[i] - mean) * rstd * g[c] + bta[c];
    if (OUT_F32)
      ((float*)outv)[(size_t)t * HH + c] = o;
    else
      ((bf16*)outv)[(size_t)t * HH + c] = f2bf(o);
  }
}

// ---- weight convert+transpose: W[K,N] f32 -> Wt[N,K] bf16 (K fixed per call) --
__global__ void convert_w_kernel(const float* __restrict__ W, bf16* __restrict__ Wt,
                                 int K, int N) {
  __shared__ float tile[32][33];
  int n0 = blockIdx.x * 32, k0 = blockIdx.y * 32;
#pragma unroll
  for (int it = 0; it < 4; it++) {
    int idx = threadIdx.x + it * 256;
    int ty = idx >> 5, tx = idx & 31;
    tile[ty][tx] = W[(size_t)(k0 + ty) * N + n0 + tx];
  }
  __syncthreads();
#pragma unroll
  for (int it = 0; it < 4; it++) {
    int idx = threadIdx.x + it * 256;
    int ty = idx >> 5, tx = idx & 31;
    Wt[(size_t)(n0 + ty) * K + k0 + tx] = f2bf(tile[tx][ty]);
  }
}

// ---- concat qkv bias: [qbias | 0 | vbias] (f32) -------------------------------
__global__ void build_qkv_bias_kernel(const float* __restrict__ qb,
                                      const float* __restrict__ vb,
                                      float* __restrict__ o) {
  int i = blockIdx.x * 256 + threadIdx.x;  // 0..3071
  float v = 0.f;
  if (i < HH) v = qb[i];
  else if (i >= 2 * HH) v = vb[i - 2 * HH];
  o[i] = v;
}

// ---- V transpose per head: qkv v-cols -> vt[b,h,dim,key] (bf16) ---------------
__global__ void transpose_v_kernel(const bf16* __restrict__ v, bf16* __restrict__ vt) {
  __shared__ unsigned short tile[32][33];
  int bh = blockIdx.z;
  int s0 = blockIdx.x * 32, d0 = blockIdx.y * 32;
  int b = bh >> 3, hd = bh & 7;
  const unsigned short* vp = (const unsigned short*)v + ((size_t)b * SS) * (3 * HH) + hd * HDD;
  unsigned short* vtp = (unsigned short*)vt + (size_t)bh * HDD * SS;
#pragma unroll
  for (int it = 0; it < 4; it++) {
    int idx = threadIdx.x + it * 256;
    int ty = idx >> 5, tx = idx & 31;
    tile[ty][tx] = vp[(size_t)(s0 + ty) * (3 * HH) + d0 + tx];
  }
  __syncthreads();
#pragma unroll
  for (int it = 0; it < 4; it++) {
    int idx = threadIdx.x + it * 256;
    int ty = idx >> 5, tx = idx & 31;
    vtp[(size_t)(d0 + ty) * SS + s0 + tx] = tile[tx][ty];
  }
}

// ---- V1: 128x128 MFMA GEMM (batched QK^T / PV), reg-staging + prefetch --------
// BK=32, 4 waves x 4x4 16x16x32 MFMA. LDS [128][32] ushorts. Chunk c of row r
// stored at c ^ ((r>>1)&3) on write AND read (uniform at 16-lane-group and
// wave granularity -> conflict-free both sides, R15-verified).
template <int GELU>
__global__ __launch_bounds__(256)
void mfma_gemm_kernel(const bf16* __restrict__ A, int lda, long long sAb, long long sAh,
                      const bf16* __restrict__ Bt, int ldb, long long sBb, long long sBh,
                      const float* __restrict__ bias,
                      bf16* __restrict__ C, int ldc, long long sCb, long long sCh,
                      int M, int N, int K, float scale) {
  __shared__ __align__(16) unsigned short Als[128 * 32];
  __shared__ __align__(16) unsigned short Bls[128 * 32];
  int tid = threadIdx.x;
  int lane = tid & 63, wave = tid >> 6;
  int l15 = lane & 15, quad = lane >> 4;
  int wm = wave & 1, wn = wave >> 1;
  int m0 = blockIdx.y * 128, n0 = blockIdx.x * 128;
  int zb = blockIdx.z >> 3, zh = blockIdx.z & 7;
  const bf16* Ab = A + zb * sAb + zh * sAh;
  const bf16* Bb = Bt + zb * sBb + zh * sBh;
  bf16* Cb = C + zb * sCb + zh * sCh;
  f4v acc[4][4];
#pragma unroll
  for (int i = 0; i < 4; i++)
#pragma unroll
    for (int j = 0; j < 4; j++) acc[i][j] = (f4v){0.f, 0.f, 0.f, 0.f};
  int r0 = tid >> 2;            // 0..63: staging rows r0, r0+64
  int q8 = (tid & 3) * 8;       // global 16B chunk offset (coalesced)
  int fw = (r0 >> 1) & 3;
  int wlo = r0 * 32 + (((tid & 3) ^ fw) * 8);
  int whi = (r0 + 64) * 32 + (((tid & 3) ^ fw) * 8);
  int qx = (quad ^ ((l15 >> 1) & 3)) * 8;
  const bf16* Ap0 = Ab + (size_t)(m0 + r0) * lda + q8;
  const bf16* Ap1 = Ab + (size_t)(m0 + r0 + 64) * lda + q8;
  const bf16* Bp0 = Bb + (size_t)(n0 + r0) * ldb + q8;
  const bf16* Bp1 = Bb + (size_t)(n0 + r0 + 64) * ldb + q8;
  uint4 a0 = *(const uint4*)(Ap0);
  uint4 a1 = *(const uint4*)(Ap1);
  uint4 b0 = *(const uint4*)(Bp0);
  uint4 b1 = *(const uint4*)(Bp1);
  for (int k0 = 0; k0 < K; k0 += 32) {
    *(uint4*)&Als[wlo] = a0;
    *(uint4*)&Als[whi] = a1;
    *(uint4*)&Bls[wlo] = b0;
    *(uint4*)&Bls[whi] = b1;
    __syncthreads();
    int kn = k0 + 32;
    if (kn < K) {           // issue next tile's loads; in flight during MFMAs
      a0 = *(const uint4*)(Ap0 + kn);
      a1 = *(const uint4*)(Ap1 + kn);
      b0 = *(const uint4*)(Bp0 + kn);
      b1 = *(const uint4*)(Bp1 + kn);
    }
    s8v af[4], bfr[4];
#pragma unroll
    for (int i = 0; i < 4; i++)
      af[i] = *(const s8v*)&Als[(wm * 64 + i * 16 + l15) * 32 + qx];
#pragma unroll
    for (int j = 0; j < 4; j++)
      bfr[j] = *(const s8v*)&Bls[(wn * 64 + j * 16 + l15) * 32 + qx];
#pragma unroll
    for (int i = 0; i < 4; i++)
#pragma unroll
      for (int j = 0; j < 4; j++)
        acc[i][j] = __builtin_amdgcn_mfma_f32_16x16x32_bf16(af[i], bfr[j], acc[i][j], 0, 0, 0);
    __syncthreads();
  }
#pragma unroll
  for (int i = 0; i < 4; i++) {
#pragma unroll
    for (int j = 0; j < 4; j++) {
      int n = n0 + wn * 64 + j * 16 + l15;
      float bval = bias ? bias[n] : 0.f;
#pragma unroll
      for (int r = 0; r < 4; r++) {
        int m = m0 + wm * 64 + i * 16 + quad * 4 + r;
        float v = (acc[i][j][r] + bval) * scale;
        if (GELU) v = 0.5f * v * (1.f + erff(v * 0.70710678118654752f));
        Cb[(size_t)m * ldc + n] = f2bf(v);
      }
    }
  }
}

// ---- V2: 128x128 MFMA GEMM (dense), gload_lds + LDS double-buffer -------------
// Stage(t+1) issued right AFTER the __syncthreads that drains tile t -> next
// drain waits on loads a full ds_read+MFMA phase old (latency hidden). Linear
// DMA dest; swizzle via global source col permutation (chunk s holds global
// chunk s ^ ((row>>1)&3)); reads as V1. Measured 89.0us @8192x3072x1024,
// 0 bank conflicts, no spill (R15).
template <int GELU>
__global__ __launch_bounds__(256)
void gemm_dbuf_kernel(const bf16* __restrict__ A, int lda,
                      const bf16* __restrict__ Bt, int ldb,
                      const float* __restrict__ bias,
                      bf16* __restrict__ C, int ldc,
                      int M, int N, int K, float scale) {
  __shared__ __align__(16) unsigned short As2[2 * 128 * 32];
  __shared__ __align__(16) unsigned short Bs2[2 * 128 * 32];
  int tid = threadIdx.x;
  int lane = tid & 63, wave = tid >> 6;
  int l15 = lane & 15, quad = lane >> 4;
  int wm = wave & 1, wn = wave >> 1;
  int m0 = blockIdx.y * 128, n0 = blockIdx.x * 128;
  f4v acc[4][4];
#pragma unroll
  for (int i = 0; i < 4; i++)
#pragma unroll
    for (int j = 0; j < 4; j++) acc[i][j] = (f4v){0.f, 0.f, 0.f, 0.f};
  int srow = tid >> 2;
  int scol = (((tid & 3) ^ ((tid >> 3) & 3))) * 8;   // inverse-swizzled src col
  const bf16* ApLo = A + (size_t)(m0 + srow) * lda + scol;
  const bf16* ApHi = A + (size_t)(m0 + srow + 64) * lda + scol;
  const bf16* BpLo = Bt + (size_t)(n0 + srow) * ldb + scol;
  const bf16* BpHi = Bt + (size_t)(n0 + srow + 64) * ldb + scol;
  int qx = (quad ^ ((l15 >> 1) & 3)) * 8;
  int niter = K >> 5;

#define V2_STAGE(kk, buf) do {                                                  \
    unsigned _o = (unsigned)(buf) * 4096u + (unsigned)tid * 8u;                 \
    __builtin_amdgcn_global_load_lds(                                           \
        (const __attribute__((address_space(1))) void*)(ApLo + (kk)),           \
        (__attribute__((address_space(3))) unsigned int*)(size_t)               \
            (unsigned)(size_t)(As2 + _o), 16, 0, 0);                            \
    __builtin_amdgcn_global_load_lds(                                           \
        (const __attribute__((address_space(1))) void*)(ApHi + (kk)),           \
        (__attribute__((address_space(3))) unsigned int*)(size_t)               \
            (unsigned)(size_t)(As2 + _o + 2048u), 16, 0, 0);                    \
    __builtin_amdgcn_global_load_lds(                                           \
        (const __attribute__((address_space(1))) void*)(BpLo + (kk)),           \
        (__attribute__((address_space(3))) unsigned int*)(size_t)               \
            (unsigned)(size_t)(Bs2 + _o), 16, 0, 0);                            \
    __builtin_amdgcn_global_load_lds(                                           \
        (const __attribute__((address_space(1))) void*)(BpHi + (kk)),           \
        (__attribute__((address_space(3))) unsigned int*)(size_t)               \
            (unsigned)(size_t)(Bs2 + _o + 2048u), 16, 0, 0);                    \
  } while (0)

  V2_STAGE(0, 0);
  for (int it = 0; it < niter; ++it) {
    __syncthreads();                     // drains vmcnt: tile it landed
    if (it + 1 < niter) V2_STAGE((it + 1) * 32, (it + 1) & 1);
    int buf = it & 1;
    s8v af[4], bfr[4];
#pragma unroll
    for (int i = 0; i < 4; i++)
      af[i] = *(const s8v*)&As2[buf * 4096 + (wm * 64 + i * 16 + l15) * 32 + qx];
#pragma unroll
    for (int j = 0; j < 4; j++)
      bfr[j] = *(const s8v*)&Bs2[buf * 4096 + (wn * 64 + j * 16 + l15) * 32 + qx];
#pragma unroll
    for (int i = 0; i < 4; i++)
#pragma unroll
      for (int j = 0; j < 4; j++)
        acc[i][j] = __builtin_amdgcn_mfma_f32_16x16x32_bf16(af[i], bfr[j], acc[i][j], 0, 0, 0);
  }
#undef V2_STAGE
#pragma unroll
  for (int i = 0; i < 4; i++) {
#pragma unroll
    for (int j = 0; j < 4; j++) {
      int n = n0 + wn * 64 + j * 16 + l15;
      float bval = bias ? bias[n] : 0.f;
#pragma unroll
      for (int r = 0; r < 4; r++) {
        int m = m0 + wm * 64 + i * 16 + quad * 4 + r;
        float v = (acc[i][j][r] + bval) * scale;
        if (GELU) v = 0.5f * v * (1.f + erff(v * 0.70710678118654752f));
        C[(size_t)m * ldc + n] = f2bf(v);
      }
    }
  }
}

// ---- softmax over last dim of scores [128*512 rows][512], bf16 in-place -------
__global__ void softmax_kernel(bf16* __restrict__ sc) {
  int wave = threadIdx.x >> 6, lane = threadIdx.x & 63;
  size_t row = (size_t)blockIdx.x * 4 + wave;
  unsigned short* p = (unsigned short*)sc + row * SS + lane * 8;
  union { uint4 u4; unsigned short u[8]; } buf;
  buf.u4 = *(const uint4*)p;
  float v[8];
  float mx = -1e30f;
#pragma unroll
  for (int j = 0; j < 8; j++) { v[j] = us2f(buf.u[j]); mx = fmaxf(mx, v[j]); }
#pragma unroll
  for (int off = 32; off > 0; off >>= 1) mx = fmaxf(mx, __shfl_xor(mx, off));
  float sum = 0.f;
#pragma unroll
  for (int j = 0; j < 8; j++) { v[j] = __expf(v[j] - mx); sum += v[j]; }
#pragma unroll
  for (int off = 32; off > 0; off >>= 1) sum += __shfl_xor(sum, off);
  float inv = 1.f / sum;
  union { uint4 u4; unsigned short u[8]; } obuf;
#pragma unroll
  for (int j = 0; j < 8; j++) {
    bf16 b = f2bf(v[j] * inv);
    obuf.u[j] = *(unsigned short*)&b;
  }
  *(uint4*)p = obuf.u4;
}

// ---------------- launch ----------------
extern "C" void kernel_launch(void* const* d_in, const int* in_sizes, int n_in,
                              void* d_out, int out_size, void* d_ws, size_t ws_size,
                              hipStream_t stream) {
  const float* x     = (const float*)d_in[0];
  const float* pos   = (const float*)d_in[1];
  const float* eg    = (const float*)d_in[2];
  const float* ebeta = (const float*)d_in[3];
  const float* Wq    = (const float*)d_in[4];
  const float* Wk    = (const float*)d_in[5];
  const float* Wv    = (const float*)d_in[6];
  const float* qbias = (const float*)d_in[7];
  const float* vbias = (const float*)d_in[8];
  const float* Wo    = (const float*)d_in[9];
  const float* bo    = (const float*)d_in[10];
  const float* l1g   = (const float*)d_in[11];
  const float* l1b   = (const float*)d_in[12];
  const float* Wi    = (const float*)d_in[13];
  const float* bi    = (const float*)d_in[14];
  const float* Wf    = (const float*)d_in[15];
  const float* bfb   = (const float*)d_in[16];
  const float* l2g   = (const float*)d_in[17];
  const float* l2b   = (const float*)d_in[18];

  // --- workspace (256 MiB): [MiB offsets] ---
  char* w = (char*)d_ws;
  const size_t MB = (size_t)1 << 20;
  bf16* h      = (bf16*)(w + 0 * MB);     // 16
  bf16* qkv    = (bf16*)(w + 16 * MB);    // 48: [T][3H] fused q|k|v
  bf16* ctx    = (bf16*)(w + 64 * MB);    // 16
  bf16* tmp1   = (bf16*)(w + 80 * MB);    // 16
  bf16* attn   = (bf16*)(w + 96 * MB);    // 16
  bf16* scores = (bf16*)(w + 112 * MB);   // 64 [112,176) live: qk->pv
  bf16* ff     = (bf16*)(w + 112 * MB);   // 48 [112,160) live: Wi->Wf (disjoint)
  bf16* tmp2   = (bf16*)(w + 176 * MB);   // 16
  bf16* vt     = (bf16*)(w + 192 * MB);   // 16
  bf16* Wqkvt  = (bf16*)(w + 208 * MB);   // 6: [3H][H] packed q|k|v rows
  bf16* Wot    = (bf16*)(w + 214 * MB);   // 2
  bf16* Wit    = (bf16*)(w + 216 * MB);   // 6
  bf16* Wft    = (bf16*)(w + 222 * MB);   // 6
  float* qkvb  = (float*)(w + 228 * MB);  // 12 KB
  float* out   = (float*)d_out;

  const float QSCALE = 0.08838834764831845f;  // 1/sqrt(128), applied in QK epilogue

  embed_ln_kernel<<<TT, 256, 0, stream>>>(x, pos, eg, ebeta, h);

  convert_w_kernel<<<dim3(HH / 32, HH / 32), 256, 0, stream>>>(Wq, Wqkvt, HH, HH);
  convert_w_kernel<<<dim3(HH / 32, HH / 32), 256, 0, stream>>>(Wk, Wqkvt + (size_t)HH * HH, HH, HH);
  convert_w_kernel<<<dim3(HH / 32, HH / 32), 256, 0, stream>>>(Wv, Wqkvt + (size_t)2 * HH * HH, HH, HH);
  convert_w_kernel<<<dim3(HH / 32, HH / 32), 256, 0, stream>>>(Wo, Wot, HH, HH);
  convert_w_kernel<<<dim3(FFF / 32, HH / 32), 256, 0, stream>>>(Wi, Wit, HH, FFF);
  convert_w_kernel<<<dim3(HH / 32, FFF / 32), 256, 0, stream>>>(Wf, Wft, FFF, HH);
  build_qkv_bias_kernel<<<12, 256, 0, stream>>>(qbias, vbias, qkvb);

  // fused QKV: qkv[8192,3072] = h @ Wqkvt^T + qkvb   (dbuf, 89.0us measured)
  gemm_dbuf_kernel<0><<<dim3(24, 64), 256, 0, stream>>>(
      h, HH, Wqkvt, HH, qkvb, qkv, 3 * HH, TT, 3 * HH, HH, 1.f);

  // scores[b,h,512,512] = (q_bh @ k_bh^T) * QSCALE  (k cols of qkv act as Bt)
  mfma_gemm_kernel<0><<<dim3(4, 4, BB * NHH), 256, 0, stream>>>(
      qkv, 3 * HH, (long long)SS * 3 * HH, HDD,
      qkv + HH, 3 * HH, (long long)SS * 3 * HH, HDD,
      nullptr,
      scores, SS, (long long)NHH * SS * SS, (long long)SS * SS,
      SS, SS, HDD, QSCALE);

  softmax_kernel<<<BB * NHH * SS / 4, 256, 0, stream>>>(scores);

  transpose_v_kernel<<<dim3(SS / 32, HDD / 32, BB * NHH), 256, 0, stream>>>(qkv + 2 * HH, vt);

  // ctx_bh[512,128] = probs_bh @ v_bh  (vt[dim][key] is Bt layout)
  mfma_gemm_kernel<0><<<dim3(1, 4, BB * NHH), 256, 0, stream>>>(
      scores, SS, (long long)NHH * SS * SS, (long long)SS * SS,
      vt, SS, (long long)NHH * HDD * SS, (long long)HDD * SS,
      nullptr,
      ctx, HH, (long long)SS * HH, HDD,
      SS, HDD, SS, 1.f);

  gemm_dbuf_kernel<0><<<dim3(8, 64), 256, 0, stream>>>(
      ctx, HH, Wot, HH, bo, tmp1, HH, TT, HH, HH, 1.f);
  add_ln_kernel<0><<<TT, 256, 0, stream>>>(tmp1, h, l1g, l1b, attn);

  gemm_dbuf_kernel<1><<<dim3(24, 64), 256, 0, stream>>>(
      attn, HH, Wit, HH, bi, ff, FFF, TT, FFF, HH, 1.f);
  gemm_dbuf_kernel<0><<<dim3(8, 64), 256, 0, stream>>>(
      ff, FFF, Wft, FFF, bfb, tmp2, HH, TT, HH, FFF, 1.f);
  add_ln_kernel<1><<<TT, 256, 0, stream>>>(tmp2, attn, l2g, l2b, out);
}